// Round 3
// baseline (73.518 us; speedup 1.0000x reference)
//
#include <hip/hip_runtime.h>
#include <hip/hip_bf16.h>

#define B_ 64
#define N_ 576
#define D_ 384
#define K_ 4096
#define BLOCKS_PER_BATCH 16
#define ROWS_PER_BLOCK (N_ / BLOCKS_PER_BATCH)  // 36

// Fused: projection (phase 1) + last-block-per-batch gather (phase 2).
// Phase 1: block g (16 per batch) projects rows [c*36, c*36+36) of batch b:
//   y[row] = { z_row.W0[:384], z_row.W1[:384], z_row.W0[384:], z_row.W1[384:] }
//   (half-wave per row, lane s owns 3 float4 columns, W held in registers)
// Phase 2: the 16th block to finish batch b gathers its 4096 pairs:
//   out[b,k,t] = y[b,i0][t] + y[b,i1][2+t] + bias[t];  idx_out = (float)indices
// Visibility: __syncthreads + tid0 __threadfence before atomicAdd (release);
// winner __threadfence before y reads (acquire). Counters reset by memset
// each call (ws is poisoned 0xAA once, never re-poisoned).
__global__ __launch_bounds__(256) void partvit_fused(const float* __restrict__ z,
                                                     const int* __restrict__ idx,
                                                     const float* __restrict__ W,
                                                     const float* __restrict__ bias,
                                                     float* __restrict__ out,
                                                     float* __restrict__ idx_out,
                                                     float* __restrict__ y,
                                                     unsigned int* __restrict__ ctr) {
    const int g = blockIdx.x;
    const int b = g >> 4;     // batch
    const int c = g & 15;     // chunk within batch
    const int tid = threadIdx.x;
    const int hw = tid >> 5;  // half-wave 0..7
    const int s  = tid & 31;  // column-chunk owner

    // W[t][f] at t*768+f. float4 view: W0[:384]=Wq[0..95], W0[384:]=Wq[96..191],
    //                                  W1[:384]=Wq[192..287], W1[384:]=Wq[288..383]
    const float4* Wq = reinterpret_cast<const float4*>(W);
    float4 w0a[3], w1a[3], w0b[3], w1b[3];
#pragma unroll
    for (int m = 0; m < 3; ++m) {
        const int c4 = s * 3 + m;
        w0a[m] = Wq[c4];
        w0b[m] = Wq[96 + c4];
        w1a[m] = Wq[192 + c4];
        w1b[m] = Wq[288 + c4];
    }

    const int row0 = b * N_ + c * ROWS_PER_BLOCK;
    const float4* zq = reinterpret_cast<const float4*>(z);

    for (int r = hw; r < ROWS_PER_BLOCK; r += 8) {
        const int row = row0 + r;
        const float4* zr = zq + (size_t)row * 96 + s * 3;
        float a0 = 0.f, a1 = 0.f, a2 = 0.f, a3 = 0.f;
#pragma unroll
        for (int m = 0; m < 3; ++m) {
            const float4 v = zr[m];
            a0 += v.x * w0a[m].x + v.y * w0a[m].y + v.z * w0a[m].z + v.w * w0a[m].w;
            a1 += v.x * w1a[m].x + v.y * w1a[m].y + v.z * w1a[m].z + v.w * w1a[m].w;
            a2 += v.x * w0b[m].x + v.y * w0b[m].y + v.z * w0b[m].z + v.w * w0b[m].w;
            a3 += v.x * w1b[m].x + v.y * w1b[m].y + v.z * w1b[m].z + v.w * w1b[m].w;
        }
#pragma unroll
        for (int off = 16; off > 0; off >>= 1) {
            a0 += __shfl_xor(a0, off);
            a1 += __shfl_xor(a1, off);
            a2 += __shfl_xor(a2, off);
            a3 += __shfl_xor(a3, off);
        }
        if (s == 0) {
            float4 v;
            v.x = a0; v.y = a1; v.z = a2; v.w = a3;
            reinterpret_cast<float4*>(y)[row] = v;
        }
    }

    // ---- signal this chunk done; last arriver gathers the batch ----
    __shared__ unsigned int old_s;
    __syncthreads();
    if (tid == 0) {
        __threadfence();                    // release: flush y writes to L3
        old_s = atomicAdd(&ctr[b], 1u);     // device-scope by default
    }
    __syncthreads();
    if (old_s != BLOCKS_PER_BATCH - 1) return;

    __threadfence();                        // acquire: don't read stale y

    const float b0 = bias[0], b1 = bias[1];
    const float* yb = y + (size_t)b * N_ * 4;
    const int base = b * K_;
    for (int i = tid; i < K_; i += 256) {
        const int t = base + i;
        const int2 p = reinterpret_cast<const int2*>(idx)[t];
        const float2 y0 = *reinterpret_cast<const float2*>(yb + (size_t)p.x * 4);      // [a0,a1] of i0
        const float2 y1 = *reinterpret_cast<const float2*>(yb + (size_t)p.y * 4 + 2);  // [a2,a3] of i1
        float2 o;
        o.x = y0.x + y1.x + b0;
        o.y = y0.y + y1.y + b1;
        reinterpret_cast<float2*>(out)[t] = o;
        float2 io;
        io.x = (float)p.x;
        io.y = (float)p.y;
        reinterpret_cast<float2*>(idx_out)[t] = io;
    }
}

extern "C" void kernel_launch(void* const* d_in, const int* in_sizes, int n_in,
                              void* d_out, int out_size, void* d_ws, size_t ws_size,
                              hipStream_t stream) {
    const float* z    = (const float*)d_in[0];
    const int*   idx  = (const int*)d_in[1];
    const float* W    = (const float*)d_in[2];
    const float* bias = (const float*)d_in[3];

    float* out     = (float*)d_out;                        // [B,K,2] floats
    float* idx_out = (float*)d_out + (size_t)B_ * K_ * 2;  // indices as float
    float* y       = (float*)d_ws;                         // [B*N,4] floats = 576 KB
    unsigned int* ctr = (unsigned int*)((char*)d_ws + (1 << 20));  // 64 counters

    // Counters must start at 0 every call (ws poisoned 0xAA once, not restored).
    hipMemsetAsync(ctr, 0, B_ * sizeof(unsigned int), stream);

    // 16 blocks per batch x 64 batches = 1024 blocks
    partvit_fused<<<B_ * BLOCKS_PER_BATCH, 256, 0, stream>>>(z, idx, W, bias,
                                                             out, idx_out, y, ctr);
}

// Round 4
// 18.710 us; speedup vs baseline: 3.9294x; 3.9294x over previous
//
#include <hip/hip_runtime.h>
#include <hip/hip_bf16.h>

#define B_ 64
#define N_ 576
#define D_ 384
#define K_ 4096

// Kernel 1: per-row projection, y[r] = { z_r.W0[:384], z_r.W1[:384], z_r.W0[384:], z_r.W1[384:] }
// Half-wave (32 lanes) per row-pair member; lane s owns float4-columns s*3..s*3+2.
// Software-pipelined: next pair's z loads issue before current pair's reduce,
// keeping >=6KB/wave in flight (need ~5.7MB chip-wide for 6.3TB/s @ ~900ns).
// 2048 blocks = 8192 waves = 32 waves/CU (VGPR ~40 -> 8 waves/SIMD OK).
__global__ __launch_bounds__(256) void partvit_proj(const float* __restrict__ z,
                                                    const float* __restrict__ W,
                                                    float* __restrict__ y) {
    const int wid  = (blockIdx.x * blockDim.x + threadIdx.x) >> 6;  // wave id
    const int lane = threadIdx.x & 63;
    const int h = lane >> 5;   // which row of the pair
    const int s = lane & 31;   // column-chunk owner within the row

    const float4* Wq = reinterpret_cast<const float4*>(W);
    const float4* zq = reinterpret_cast<const float4*>(z);
    const int c4 = s * 3;

    const int npairs = (B_ * N_) / 2;                       // 18432 row-pairs
    const int nwaves = (gridDim.x * blockDim.x) >> 6;

    int pid = wid;
    if (pid >= npairs) return;

    float4 v0, v1, v2;
    {
        const float4* zr = zq + (size_t)(pid * 2 + h) * 96 + c4;
        v0 = zr[0]; v1 = zr[1]; v2 = zr[2];
    }

    while (true) {
        const int next = pid + nwaves;
        const bool has_next = next < npairs;
        float4 n0, n1, n2;
        if (has_next) {
            const float4* zr = zq + (size_t)(next * 2 + h) * 96 + c4;
            n0 = zr[0]; n1 = zr[1]; n2 = zr[2];   // in flight during reduce below
        }

        // W[t][f] at t*768+f. float4 view: W0[:384]=Wq[0..95], W0[384:]=Wq[96..191],
        //                                  W1[:384]=Wq[192..287], W1[384:]=Wq[288..383]
        float a0, a1, a2, a3;
        {
            const float4 wa = Wq[c4],     wb = Wq[c4 + 1],     wc = Wq[c4 + 2];
            a0 = v0.x*wa.x + v0.y*wa.y + v0.z*wa.z + v0.w*wa.w
               + v1.x*wb.x + v1.y*wb.y + v1.z*wb.z + v1.w*wb.w
               + v2.x*wc.x + v2.y*wc.y + v2.z*wc.z + v2.w*wc.w;
        }
        {
            const float4 wa = Wq[192+c4], wb = Wq[192+c4+1],   wc = Wq[192+c4+2];
            a1 = v0.x*wa.x + v0.y*wa.y + v0.z*wa.z + v0.w*wa.w
               + v1.x*wb.x + v1.y*wb.y + v1.z*wb.z + v1.w*wb.w
               + v2.x*wc.x + v2.y*wc.y + v2.z*wc.z + v2.w*wc.w;
        }
        {
            const float4 wa = Wq[96+c4],  wb = Wq[96+c4+1],    wc = Wq[96+c4+2];
            a2 = v0.x*wa.x + v0.y*wa.y + v0.z*wa.z + v0.w*wa.w
               + v1.x*wb.x + v1.y*wb.y + v1.z*wb.z + v1.w*wb.w
               + v2.x*wc.x + v2.y*wc.y + v2.z*wc.z + v2.w*wc.w;
        }
        {
            const float4 wa = Wq[288+c4], wb = Wq[288+c4+1],   wc = Wq[288+c4+2];
            a3 = v0.x*wa.x + v0.y*wa.y + v0.z*wa.z + v0.w*wa.w
               + v1.x*wb.x + v1.y*wb.y + v1.z*wb.z + v1.w*wb.w
               + v2.x*wc.x + v2.y*wc.y + v2.z*wc.z + v2.w*wc.w;
        }

        // reduce across the 32 lanes of this half-wave
#pragma unroll
        for (int off = 16; off > 0; off >>= 1) {
            a0 += __shfl_xor(a0, off);
            a1 += __shfl_xor(a1, off);
            a2 += __shfl_xor(a2, off);
            a3 += __shfl_xor(a3, off);
        }
        if (s == 0) {
            float4 o;
            o.x = a0; o.y = a1; o.z = a2; o.w = a3;
            reinterpret_cast<float4*>(y)[pid * 2 + h] = o;
        }

        if (!has_next) break;
        pid = next;
        v0 = n0; v1 = n1; v2 = n2;
    }
}

// Kernel 2: gather + bias + index pass-through.
// out[b,k,t]      = y[b,i0][t] + y[b,i1][2+t] + bias[t]
// idx_out[b,k,m]  = (float)indices[b,k,m]
__global__ __launch_bounds__(256) void partvit_gather(const int* __restrict__ idx,
                                                      const float* __restrict__ y,
                                                      const float* __restrict__ bias,
                                                      float* __restrict__ out,
                                                      float* __restrict__ idx_out) {
    const int t = blockIdx.x * blockDim.x + threadIdx.x;  // pair id in [0, B*K)
    if (t >= B_ * K_) return;
    const int b = t >> 12;  // K = 4096

    const int2 p = reinterpret_cast<const int2*>(idx)[t];
    const float* yb = y + (size_t)b * N_ * 4;

    const float2 y0 = *reinterpret_cast<const float2*>(yb + (size_t)p.x * 4);      // [a0,a1] of i0
    const float2 y1 = *reinterpret_cast<const float2*>(yb + (size_t)p.y * 4 + 2);  // [a2,a3] of i1

    const float b0 = bias[0], b1 = bias[1];

    float2 o;
    o.x = y0.x + y1.x + b0;
    o.y = y0.y + y1.y + b1;
    reinterpret_cast<float2*>(out)[t] = o;

    float2 io;
    io.x = (float)p.x;
    io.y = (float)p.y;
    reinterpret_cast<float2*>(idx_out)[t] = io;
}

extern "C" void kernel_launch(void* const* d_in, const int* in_sizes, int n_in,
                              void* d_out, int out_size, void* d_ws, size_t ws_size,
                              hipStream_t stream) {
    const float* z    = (const float*)d_in[0];
    const int*   idx  = (const int*)d_in[1];
    const float* W    = (const float*)d_in[2];
    const float* bias = (const float*)d_in[3];

    float* out     = (float*)d_out;                        // [B,K,2] floats
    float* idx_out = (float*)d_out + (size_t)B_ * K_ * 2;  // indices as float
    float* y       = (float*)d_ws;                         // [B*N,4] floats = 576 KB

    // Kernel 1: 8192 waves grid-striding over 18432 row-pairs (32 waves/CU)
    partvit_proj<<<2048, 256, 0, stream>>>(z, W, y);

    // Kernel 2: 262144 pairs, 1 thread/pair -> 1024 blocks
    const int pairs = B_ * K_;
    partvit_gather<<<(pairs + 255) / 256, 256, 0, stream>>>(idx, y, bias, out, idx_out);
}